// Round 2
// baseline (371.306 us; speedup 1.0000x reference)
//
#include <hip/hip_runtime.h>
#include <stdint.h>

#define BATCH    256
#define VOCAB    128000
#define HIST     200
#define TOPK     50
#define CAP      2048
#define MINCNT   250          // guarantee threshold: >=250 raw => superset of post-penalty top-k
#define T_RAW    2.6f         // expected count(v>2.6) ~ 596 per row for N(0,1)
#define CHUNKS_PER_ROW 8
#define P1_THREADS 256
#define P2_THREADS 512
#define BITWORDS (VOCAB / 32) // 4000 words = 16000 B

typedef float vfloat4 __attribute__((ext_vector_type(4)));

// Monotonic float->uint key: descending float order == descending unsigned order.
__device__ __forceinline__ unsigned fkey_of(float f) {
  unsigned u = __float_as_uint(f);
  return (u & 0x80000000u) ? ~u : (u | 0x80000000u);
}
__device__ __forceinline__ float f_of_key(unsigned k) {
  unsigned u = (k & 0x80000000u) ? (k & 0x7FFFFFFFu) : ~k;
  return __uint_as_float(u);
}

// ---------------- Phase 1: stream read + zero-write + raw candidate collect ----------------
__global__ __launch_bounds__(P1_THREADS) void phase1_kernel(
    const float* __restrict__ logits, float* __restrict__ out,
    int* __restrict__ cnt_g, unsigned long long* __restrict__ cand)
{
  const int blk = blockIdx.x;
  const int b   = blk / CHUNKS_PER_ROW;
  const int c   = blk % CHUNKS_PER_ROW;
  const int CH4 = VOCAB / 4 / CHUNKS_PER_ROW;   // 4000 float4 per chunk

  const float4*  row4  = (const float4*)(logits + (size_t)b * VOCAB) + (size_t)c * CH4;
  vfloat4*       orow4 = (vfloat4*)(out + (size_t)b * VOCAB) + (size_t)c * CH4;
  const int base_idx = c * CH4 * 4;

  const vfloat4 zero4 = {0.f, 0.f, 0.f, 0.f};
  for (int i = threadIdx.x; i < CH4; i += P1_THREADS) {
    float4 v4 = row4[i];
    __builtin_nontemporal_store(zero4, &orow4[i]);
    float vv[4] = {v4.x, v4.y, v4.z, v4.w};
    #pragma unroll
    for (int l = 0; l < 4; ++l) {
      float v = vv[l];
      if (v > T_RAW) {                 // raw superset; penalty/temp applied in phase 2
        int pos = atomicAdd(&cnt_g[b], 1);
        if (pos < CAP) {
          cand[(size_t)b * CAP + pos] =
              ((unsigned long long)fkey_of(v) << 32) |
              (unsigned)(~(unsigned)(base_idx + i * 4 + l));  // tie-break: smaller idx first
        }
      }
    }
  }
}

// ---------------- Phase 2: per-row penalty + sort + topk/topp + scatter ----------------
__global__ __launch_bounds__(P2_THREADS) void phase2_kernel(
    const float* __restrict__ logits, const int* __restrict__ prev,
    float* __restrict__ out, const int* __restrict__ cnt_g,
    const unsigned long long* __restrict__ cand)
{
  __shared__ unsigned bitmask[BITWORDS];          // 16000 B
  __shared__ unsigned long long keys[CAP];        // 16384 B
  __shared__ float evals[CAP];                    //  8192 B
  __shared__ int s_cnt, s_m, s_j;
  __shared__ float s_Z2;

  const int b = blockIdx.x, tid = threadIdx.x;

  // seen-token bitmask
  for (int i = tid; i < BITWORDS; i += P2_THREADS) bitmask[i] = 0u;
  __syncthreads();
  for (int i = tid; i < HIST; i += P2_THREADS) {
    int t = prev[b * HIST + i];
    atomicOr(&bitmask[t >> 5], 1u << (t & 31));
  }
  __syncthreads();

  const int cnt_raw = cnt_g[b];   // block-uniform
  if (cnt_raw >= MINCNT && cnt_raw <= CAP) {
    // fast path: penalize + temperature on collected candidates only
    for (int i = tid; i < cnt_raw; i += P2_THREADS) {
      unsigned long long key = cand[(size_t)b * CAP + i];
      unsigned iv = (unsigned)(key & 0xFFFFFFFFull);
      int idx = (int)(~iv);
      float v = f_of_key((unsigned)(key >> 32));
      float y = v;
      if ((bitmask[idx >> 5] >> (idx & 31)) & 1u)
        y = (v < 0.0f) ? v * 1.2f : v / 1.2f;
      float x = y / 0.6f;
      keys[i] = ((unsigned long long)fkey_of(x) << 32) | iv;
    }
    if (tid == 0) s_cnt = cnt_raw;
    __syncthreads();
  } else {
    // robust fallback: rescan row with bisection on post-penalty threshold
    const float* row = logits + (size_t)b * VOCAB;
    float T = 3.0f, Tlo = 0.f, Thi = 0.f;
    bool hasLo = false, hasHi = false;
    int c2 = 0;
    for (int attempt = 0; attempt < 40; ++attempt) {
      __syncthreads();
      if (tid == 0) s_cnt = 0;
      __syncthreads();
      for (int i = tid; i < VOCAB; i += P2_THREADS) {
        float v = row[i];
        float y = v;
        if ((bitmask[i >> 5] >> (i & 31)) & 1u)
          y = (v < 0.0f) ? v * 1.2f : v / 1.2f;
        if (y > T) {
          int pos = atomicAdd(&s_cnt, 1);
          if (pos < CAP) {
            float x = y / 0.6f;
            keys[pos] = ((unsigned long long)fkey_of(x) << 32) |
                        (unsigned)(~(unsigned)i);
          }
        }
      }
      __syncthreads();
      c2 = s_cnt;
      if (c2 >= TOPK && c2 <= CAP) break;
      if (c2 < TOPK) { Thi = T; hasHi = true; T = hasLo ? 0.5f * (T + Tlo) : T - 1.0f; }
      else           { Tlo = T; hasLo = true; T = hasHi ? 0.5f * (T + Thi) : T + 1.0f; }
    }
    __syncthreads();
    if (tid == 0 && s_cnt > CAP) s_cnt = CAP;
    __syncthreads();
  }
  const int m_cnt = s_cnt;

  // bitonic sort descending, padded to pow2
  int n = 64;
  while (n < m_cnt) n <<= 1;
  for (int i = m_cnt + tid; i < n; i += P2_THREADS) keys[i] = 0ull;
  __syncthreads();
  for (int k = 2; k <= n; k <<= 1) {
    for (int j = k >> 1; j > 0; j >>= 1) {
      for (int i = tid; i < n; i += P2_THREADS) {
        int l = i ^ j;
        if (l > i) {
          unsigned long long a = keys[i], cc = keys[l];
          bool up = (i & k) == 0;
          if (up ? (a < cc) : (a > cc)) { keys[i] = cc; keys[l] = a; }
        }
      }
      __syncthreads();
    }
  }

  // top-k boundary (keep ties at kth)
  if (tid == 0) {
    int kk = (m_cnt < TOPK) ? m_cnt : TOPK;
    unsigned kth = (unsigned)(keys[kk - 1] >> 32);
    int m = kk;
    while (m < m_cnt && (unsigned)(keys[m] >> 32) == kth) m++;
    s_m = m;
  }
  __syncthreads();
  const int m = s_m;
  const float maxx = f_of_key((unsigned)(keys[0] >> 32));
  for (int i = tid; i < m; i += P2_THREADS)
    evals[i] = expf(f_of_key((unsigned)(keys[i] >> 32)) - maxx);
  __syncthreads();

  // nucleus cutoff: keep token i iff i==0 or cumsum(p[0..i-1]) <= 0.9
  if (tid == 0) {
    float Z = 0.f;
    for (int i = 0; i < m; ++i) Z += evals[i];
    float cum = 0.f;
    int j = 0;
    for (int i = 0; i < m; ++i) {
      if (i > 0 && cum > 0.9f) break;
      cum += evals[i] / Z;
      j = i + 1;
    }
    float Z2 = 0.f;
    for (int i = 0; i < j; ++i) Z2 += evals[i];
    s_j = j; s_Z2 = Z2;
  }
  __syncthreads();

  // scatter final probs (row already zeroed by phase 1)
  for (int i = tid; i < s_j; i += P2_THREADS) {
    int idx = (int)(~(unsigned)(keys[i] & 0xFFFFFFFFull));
    out[(size_t)b * VOCAB + idx] = evals[i] / s_Z2;
  }
}

// ---------------- Legacy single-kernel path (ws_size fallback) ----------------
__global__ __launch_bounds__(1024) void sample_head_kernel(
    const float* __restrict__ logits, const int* __restrict__ prev,
    float* __restrict__ out)
{
  __shared__ unsigned bitmask[BITWORDS];
  __shared__ unsigned long long keys[CAP];
  __shared__ float evals[CAP];
  __shared__ int s_count;
  __shared__ int s_m, s_j;
  __shared__ float s_maxx, s_Z2;

  const int b   = blockIdx.x;
  const int tid = threadIdx.x;
  const float* row  = logits + (size_t)b * VOCAB;
  float*       orow = out    + (size_t)b * VOCAB;

  for (int i = tid; i < BITWORDS; i += 1024) bitmask[i] = 0u;
  __syncthreads();
  for (int i = tid; i < HIST; i += 1024) {
    int t = prev[b * HIST + i];
    atomicOr(&bitmask[t >> 5], 1u << (t & 31));
  }
  __syncthreads();

  float T = 3.0f;
  float Tlo = 0.f, Thi = 0.f;
  bool hasLo = false, hasHi = false;
  int cnt = 0;

  const float4* row4  = (const float4*)row;
  float4*       orow4 = (float4*)orow;
  const int N4 = VOCAB / 4;

  for (int attempt = 0; attempt < 40; ++attempt) {
    __syncthreads();
    if (tid == 0) s_count = 0;
    __syncthreads();
    for (int i = tid; i < N4; i += 1024) {
      float4 v4 = row4[i];
      if (attempt == 0) orow4[i] = make_float4(0.f, 0.f, 0.f, 0.f);
      int v0 = i * 4;
      unsigned w  = bitmask[v0 >> 5];
      unsigned sh = v0 & 31;
      float vv[4] = {v4.x, v4.y, v4.z, v4.w};
      #pragma unroll
      for (int l = 0; l < 4; ++l) {
        float v = vv[l];
        float y = v;
        if ((w >> (sh + l)) & 1u)
          y = (v < 0.0f) ? v * 1.2f : v / 1.2f;
        if (y > T) {
          float x = y / 0.6f;
          int pos = atomicAdd(&s_count, 1);
          if (pos < CAP) {
            keys[pos] = ((unsigned long long)fkey_of(x) << 32) |
                        (unsigned)(~(unsigned)(v0 + l));
          }
        }
      }
    }
    __syncthreads();
    cnt = s_count;
    if (cnt >= TOPK && cnt <= CAP) break;
    if (cnt < TOPK) { Thi = T; hasHi = true; T = hasLo ? 0.5f * (T + Tlo) : T - 1.0f; }
    else            { Tlo = T; hasLo = true; T = hasHi ? 0.5f * (T + Thi) : T + 1.0f; }
  }
  if (cnt > CAP) cnt = CAP;

  int n = 64;
  while (n < cnt) n <<= 1;
  for (int i = cnt + tid; i < n; i += 1024) keys[i] = 0ull;
  __syncthreads();
  for (int k = 2; k <= n; k <<= 1) {
    for (int j = k >> 1; j > 0; j >>= 1) {
      for (int i = tid; i < n; i += 1024) {
        int l = i ^ j;
        if (l > i) {
          unsigned long long a = keys[i], c = keys[l];
          bool up = (i & k) == 0;
          if (up ? (a < c) : (a > c)) { keys[i] = c; keys[l] = a; }
        }
      }
      __syncthreads();
    }
  }

  if (tid == 0) {
    int kk = (cnt < TOPK) ? cnt : TOPK;
    unsigned kth = (unsigned)(keys[kk - 1] >> 32);
    int m = kk;
    while (m < cnt && (unsigned)(keys[m] >> 32) == kth) m++;
    s_m = m;
    s_maxx = f_of_key((unsigned)(keys[0] >> 32));
  }
  __syncthreads();
  int m = s_m;
  float maxx = s_maxx;
  for (int i = tid; i < m; i += 1024)
    evals[i] = expf(f_of_key((unsigned)(keys[i] >> 32)) - maxx);
  __syncthreads();

  if (tid == 0) {
    float Z = 0.f;
    for (int i = 0; i < m; ++i) Z += evals[i];
    float cum = 0.f;
    int j = 0;
    for (int i = 0; i < m; ++i) {
      if (i > 0 && cum > 0.9f) break;
      cum += evals[i] / Z;
      j = i + 1;
    }
    float Z2 = 0.f;
    for (int i = 0; i < j; ++i) Z2 += evals[i];
    s_j = j; s_Z2 = Z2;
  }
  __syncthreads();

  int j = s_j;
  float Z2 = s_Z2;
  for (int i = tid; i < j; i += 1024) {
    int idx = (int)(~(unsigned)(keys[i] & 0xFFFFFFFFull));
    orow[idx] = evals[i] / Z2;
  }
}

extern "C" void kernel_launch(void* const* d_in, const int* in_sizes, int n_in,
                              void* d_out, int out_size, void* d_ws, size_t ws_size,
                              hipStream_t stream) {
  const float* logits = (const float*)d_in[0];
  const int*   prev   = (const int*)d_in[1];
  float*       out    = (float*)d_out;

  const size_t need = 1024 + (size_t)BATCH * CAP * sizeof(unsigned long long);
  if (ws_size >= need) {
    int* cnt = (int*)d_ws;
    unsigned long long* cand = (unsigned long long*)((char*)d_ws + 1024);
    hipMemsetAsync(d_ws, 0, BATCH * sizeof(int), stream);
    hipLaunchKernelGGL(phase1_kernel, dim3(BATCH * CHUNKS_PER_ROW), dim3(P1_THREADS),
                       0, stream, logits, out, cnt, cand);
    hipLaunchKernelGGL(phase2_kernel, dim3(BATCH), dim3(P2_THREADS),
                       0, stream, logits, prev, out, cnt, cand);
  } else {
    hipLaunchKernelGGL(sample_head_kernel, dim3(BATCH), dim3(1024), 0, stream,
                       logits, prev, out);
  }
}

// Round 3
// 264.233 us; speedup vs baseline: 1.4052x; 1.4052x over previous
//
#include <hip/hip_runtime.h>
#include <stdint.h>

#define BATCH    256
#define VOCAB    128000
#define HIST     200
#define TOPK     50
#define CAP      2048
#define MINCNT   250          // >=250 raw candidates => superset of post-penalty top-k
#define T_RAW    2.6f         // expected count(v>2.6) ~ 596 per row for N(0,1)
#define CHUNKS_PER_ROW 8
#define P1_THREADS 512
#define F4T      8            // float4 per thread (8 x 16B = 128B)
#define CH4      (VOCAB / 4 / CHUNKS_PER_ROW)   // 4000 float4 per block
#define LOCCAP   768
#define P2_THREADS 512
#define BITWORDS (VOCAB / 32) // 4000 words = 16000 B

typedef unsigned long long ull;

// Monotonic float->uint key: descending float order == descending unsigned order.
__device__ __forceinline__ unsigned fkey_of(float f) {
  unsigned u = __float_as_uint(f);
  return (u & 0x80000000u) ? ~u : (u | 0x80000000u);
}
__device__ __forceinline__ float f_of_key(unsigned k) {
  unsigned u = (k & 0x80000000u) ? (k & 0x7FFFFFFFu) : ~k;
  return __uint_as_float(u);
}

// ---------------- Phase 1: MLP-friendly stream: batched loads, batched zero
// stores, register-space scan, LDS candidate buffer, one global atomic/block.
__global__ __launch_bounds__(P1_THREADS) void phase1_kernel(
    const float* __restrict__ logits, float* __restrict__ out,
    int* __restrict__ cnt_g, ull* __restrict__ cand)
{
  __shared__ ull cand_loc[LOCCAP];
  __shared__ int s_n, s_base;
  if (threadIdx.x == 0) s_n = 0;
  __syncthreads();

  const int blk = blockIdx.x;
  const int b   = blk >> 3;          // / CHUNKS_PER_ROW
  const int c   = blk & 7;
  const float4* row4  = (const float4*)(logits + (size_t)b * VOCAB) + (size_t)c * CH4;
  float4*       orow4 = (float4*)(out + (size_t)b * VOCAB) + (size_t)c * CH4;
  const int base_idx = c * CH4 * 4;
  const int t = threadIdx.x;

  // ---- batched independent loads (8 outstanding per thread) ----
  float4 vals[F4T];
  #pragma unroll
  for (int u = 0; u < F4T; ++u) {
    int i = t + u * P1_THREADS;
    vals[u] = (i < CH4) ? row4[i]
                        : make_float4(-1e30f, -1e30f, -1e30f, -1e30f);
  }
  // ---- batched zero stores (independent of loads) ----
  const float4 z = make_float4(0.f, 0.f, 0.f, 0.f);
  #pragma unroll
  for (int u = 0; u < F4T; ++u) {
    int i = t + u * P1_THREADS;
    if (i < CH4) orow4[i] = z;
  }
  // ---- register-space scan; rare LDS append ----
  #pragma unroll
  for (int u = 0; u < F4T; ++u) {
    int i = t + u * P1_THREADS;
    float vv[4] = {vals[u].x, vals[u].y, vals[u].z, vals[u].w};
    #pragma unroll
    for (int l = 0; l < 4; ++l) {
      if (vv[l] > T_RAW) {
        int p = atomicAdd(&s_n, 1);
        if (p < LOCCAP)
          cand_loc[p] = ((ull)fkey_of(vv[l]) << 32) |
                        (unsigned)(~(unsigned)(base_idx + i * 4 + l));
      }
    }
  }
  __syncthreads();

  // ---- flush to per-row global list ----
  int n = s_n;
  bool overflow = (n > LOCCAP);
  if (overflow) n = LOCCAP;
  if (threadIdx.x == 0)
    s_base = atomicAdd(&cnt_g[b], n + (overflow ? (1 << 20) : 0));
  __syncthreads();
  const int base = s_base;
  for (int i = threadIdx.x; i < n; i += P1_THREADS) {
    int p = base + i;
    if (p < CAP) cand[(size_t)b * CAP + p] = cand_loc[i];
  }
}

// ---------------- Phase 2: per-row penalty + sort + topk/topp + scatter ----------------
__global__ __launch_bounds__(P2_THREADS) void phase2_kernel(
    const float* __restrict__ logits, const int* __restrict__ prev,
    float* __restrict__ out, const int* __restrict__ cnt_g,
    const ull* __restrict__ cand)
{
  __shared__ unsigned bitmask[BITWORDS];          // 16000 B
  __shared__ ull keys[CAP];                       // 16384 B
  __shared__ float evals[CAP];                    //  8192 B
  __shared__ int s_cnt, s_m, s_j;
  __shared__ float s_Z2;

  const int b = blockIdx.x, tid = threadIdx.x;

  // seen-token bitmask
  for (int i = tid; i < BITWORDS; i += P2_THREADS) bitmask[i] = 0u;
  __syncthreads();
  for (int i = tid; i < HIST; i += P2_THREADS) {
    int t = prev[b * HIST + i];
    atomicOr(&bitmask[t >> 5], 1u << (t & 31));
  }
  __syncthreads();

  const int cnt_raw = cnt_g[b];   // block-uniform
  if (cnt_raw >= MINCNT && cnt_raw <= CAP) {
    // fast path: penalize + temperature on collected candidates only
    for (int i = tid; i < cnt_raw; i += P2_THREADS) {
      ull key = cand[(size_t)b * CAP + i];
      unsigned iv = (unsigned)(key & 0xFFFFFFFFull);
      int idx = (int)(~iv);
      float v = f_of_key((unsigned)(key >> 32));
      float y = v;
      if ((bitmask[idx >> 5] >> (idx & 31)) & 1u)
        y = (v < 0.0f) ? v * 1.2f : v / 1.2f;
      float x = y / 0.6f;
      keys[i] = ((ull)fkey_of(x) << 32) | iv;
    }
    if (tid == 0) s_cnt = cnt_raw;
    __syncthreads();
  } else {
    // robust fallback: rescan row with bisection on post-penalty threshold
    const float* row = logits + (size_t)b * VOCAB;
    float T = 3.0f, Tlo = 0.f, Thi = 0.f;
    bool hasLo = false, hasHi = false;
    int c2 = 0;
    for (int attempt = 0; attempt < 40; ++attempt) {
      __syncthreads();
      if (tid == 0) s_cnt = 0;
      __syncthreads();
      for (int i = tid; i < VOCAB; i += P2_THREADS) {
        float v = row[i];
        float y = v;
        if ((bitmask[i >> 5] >> (i & 31)) & 1u)
          y = (v < 0.0f) ? v * 1.2f : v / 1.2f;
        if (y > T) {
          int pos = atomicAdd(&s_cnt, 1);
          if (pos < CAP) {
            float x = y / 0.6f;
            keys[pos] = ((ull)fkey_of(x) << 32) | (unsigned)(~(unsigned)i);
          }
        }
      }
      __syncthreads();
      c2 = s_cnt;
      if (c2 >= TOPK && c2 <= CAP) break;
      if (c2 < TOPK) { Thi = T; hasHi = true; T = hasLo ? 0.5f * (T + Tlo) : T - 1.0f; }
      else           { Tlo = T; hasLo = true; T = hasHi ? 0.5f * (T + Thi) : T + 1.0f; }
    }
    __syncthreads();
    if (tid == 0 && s_cnt > CAP) s_cnt = CAP;
    __syncthreads();
  }
  const int m_cnt = s_cnt;

  // bitonic sort descending, padded to pow2
  int n = 64;
  while (n < m_cnt) n <<= 1;
  for (int i = m_cnt + tid; i < n; i += P2_THREADS) keys[i] = 0ull;
  __syncthreads();
  for (int k = 2; k <= n; k <<= 1) {
    for (int j = k >> 1; j > 0; j >>= 1) {
      for (int i = tid; i < n; i += P2_THREADS) {
        int l = i ^ j;
        if (l > i) {
          ull a = keys[i], cc = keys[l];
          bool up = (i & k) == 0;
          if (up ? (a < cc) : (a > cc)) { keys[i] = cc; keys[l] = a; }
        }
      }
      __syncthreads();
    }
  }

  // top-k boundary (keep ties at kth)
  if (tid == 0) {
    int kk = (m_cnt < TOPK) ? m_cnt : TOPK;
    unsigned kth = (unsigned)(keys[kk - 1] >> 32);
    int m = kk;
    while (m < m_cnt && (unsigned)(keys[m] >> 32) == kth) m++;
    s_m = m;
  }
  __syncthreads();
  const int m = s_m;
  const float maxx = f_of_key((unsigned)(keys[0] >> 32));
  for (int i = tid; i < m; i += P2_THREADS)
    evals[i] = expf(f_of_key((unsigned)(keys[i] >> 32)) - maxx);
  __syncthreads();

  // nucleus cutoff: keep token i iff i==0 or cumsum(p[0..i-1]) <= 0.9
  if (tid == 0) {
    float Z = 0.f;
    for (int i = 0; i < m; ++i) Z += evals[i];
    float cum = 0.f;
    int j = 0;
    for (int i = 0; i < m; ++i) {
      if (i > 0 && cum > 0.9f) break;
      cum += evals[i] / Z;
      j = i + 1;
    }
    float Z2 = 0.f;
    for (int i = 0; i < j; ++i) Z2 += evals[i];
    s_j = j; s_Z2 = Z2;
  }
  __syncthreads();

  // scatter final probs (row already zeroed by phase 1)
  for (int i = tid; i < s_j; i += P2_THREADS) {
    int idx = (int)(~(unsigned)(keys[i] & 0xFFFFFFFFull));
    out[(size_t)b * VOCAB + idx] = evals[i] / s_Z2;
  }
}

// ---------------- Legacy single-kernel path (ws_size fallback) ----------------
__global__ __launch_bounds__(1024) void sample_head_kernel(
    const float* __restrict__ logits, const int* __restrict__ prev,
    float* __restrict__ out)
{
  __shared__ unsigned bitmask[BITWORDS];
  __shared__ ull keys[CAP];
  __shared__ float evals[CAP];
  __shared__ int s_count;
  __shared__ int s_m, s_j;
  __shared__ float s_maxx, s_Z2;

  const int b   = blockIdx.x;
  const int tid = threadIdx.x;
  const float* row  = logits + (size_t)b * VOCAB;
  float*       orow = out    + (size_t)b * VOCAB;

  for (int i = tid; i < BITWORDS; i += 1024) bitmask[i] = 0u;
  __syncthreads();
  for (int i = tid; i < HIST; i += 1024) {
    int t = prev[b * HIST + i];
    atomicOr(&bitmask[t >> 5], 1u << (t & 31));
  }
  __syncthreads();

  float T = 3.0f;
  float Tlo = 0.f, Thi = 0.f;
  bool hasLo = false, hasHi = false;
  int cnt = 0;

  const float4* row4  = (const float4*)row;
  float4*       orow4 = (float4*)orow;
  const int N4 = VOCAB / 4;

  for (int attempt = 0; attempt < 40; ++attempt) {
    __syncthreads();
    if (tid == 0) s_count = 0;
    __syncthreads();
    for (int i = tid; i < N4; i += 1024) {
      float4 v4 = row4[i];
      if (attempt == 0) orow4[i] = make_float4(0.f, 0.f, 0.f, 0.f);
      int v0 = i * 4;
      unsigned w  = bitmask[v0 >> 5];
      unsigned sh = v0 & 31;
      float vv[4] = {v4.x, v4.y, v4.z, v4.w};
      #pragma unroll
      for (int l = 0; l < 4; ++l) {
        float v = vv[l];
        float y = v;
        if ((w >> (sh + l)) & 1u)
          y = (v < 0.0f) ? v * 1.2f : v / 1.2f;
        if (y > T) {
          float x = y / 0.6f;
          int pos = atomicAdd(&s_count, 1);
          if (pos < CAP) {
            keys[pos] = ((ull)fkey_of(x) << 32) | (unsigned)(~(unsigned)(v0 + l));
          }
        }
      }
    }
    __syncthreads();
    cnt = s_count;
    if (cnt >= TOPK && cnt <= CAP) break;
    if (cnt < TOPK) { Thi = T; hasHi = true; T = hasLo ? 0.5f * (T + Tlo) : T - 1.0f; }
    else            { Tlo = T; hasLo = true; T = hasHi ? 0.5f * (T + Thi) : T + 1.0f; }
  }
  if (cnt > CAP) cnt = CAP;

  int n = 64;
  while (n < cnt) n <<= 1;
  for (int i = cnt + tid; i < n; i += 1024) keys[i] = 0ull;
  __syncthreads();
  for (int k = 2; k <= n; k <<= 1) {
    for (int j = k >> 1; j > 0; j >>= 1) {
      for (int i = tid; i < n; i += 1024) {
        int l = i ^ j;
        if (l > i) {
          ull a = keys[i], c = keys[l];
          bool up = (i & k) == 0;
          if (up ? (a < c) : (a > c)) { keys[i] = c; keys[l] = a; }
        }
      }
      __syncthreads();
    }
  }

  if (tid == 0) {
    int kk = (cnt < TOPK) ? cnt : TOPK;
    unsigned kth = (unsigned)(keys[kk - 1] >> 32);
    int m = kk;
    while (m < cnt && (unsigned)(keys[m] >> 32) == kth) m++;
    s_m = m;
    s_maxx = f_of_key((unsigned)(keys[0] >> 32));
  }
  __syncthreads();
  int m = s_m;
  float maxx = s_maxx;
  for (int i = tid; i < m; i += 1024)
    evals[i] = expf(f_of_key((unsigned)(keys[i] >> 32)) - maxx);
  __syncthreads();

  if (tid == 0) {
    float Z = 0.f;
    for (int i = 0; i < m; ++i) Z += evals[i];
    float cum = 0.f;
    int j = 0;
    for (int i = 0; i < m; ++i) {
      if (i > 0 && cum > 0.9f) break;
      cum += evals[i] / Z;
      j = i + 1;
    }
    float Z2 = 0.f;
    for (int i = 0; i < j; ++i) Z2 += evals[i];
    s_j = j; s_Z2 = Z2;
  }
  __syncthreads();

  int j = s_j;
  float Z2 = s_Z2;
  for (int i = tid; i < j; i += 1024) {
    int idx = (int)(~(unsigned)(keys[i] & 0xFFFFFFFFull));
    orow[idx] = evals[i] / Z2;
  }
}

extern "C" void kernel_launch(void* const* d_in, const int* in_sizes, int n_in,
                              void* d_out, int out_size, void* d_ws, size_t ws_size,
                              hipStream_t stream) {
  const float* logits = (const float*)d_in[0];
  const int*   prev   = (const int*)d_in[1];
  float*       out    = (float*)d_out;

  const size_t need = 1024 + (size_t)BATCH * CAP * sizeof(ull);
  if (ws_size >= need) {
    int* cnt = (int*)d_ws;
    ull* cand = (ull*)((char*)d_ws + 1024);
    hipMemsetAsync(d_ws, 0, BATCH * sizeof(int), stream);
    hipLaunchKernelGGL(phase1_kernel, dim3(BATCH * CHUNKS_PER_ROW), dim3(P1_THREADS),
                       0, stream, logits, out, cnt, cand);
    hipLaunchKernelGGL(phase2_kernel, dim3(BATCH), dim3(P2_THREADS),
                       0, stream, logits, prev, out, cnt, cand);
  } else {
    hipLaunchKernelGGL(sample_head_kernel, dim3(BATCH), dim3(1024), 0, stream,
                       logits, prev, out);
  }
}

// Round 4
// 261.178 us; speedup vs baseline: 1.4217x; 1.0117x over previous
//
#include <hip/hip_runtime.h>
#include <stdint.h>

#define BATCH    256
#define VOCAB    128000
#define HIST     200
#define TOPK     50
#define CAP      2048
#define MINCNT   250          // >=250 raw candidates => superset of post-penalty top-k
#define T_RAW    2.6f         // expected count(v>2.6) ~ 596 per row for N(0,1)
#define CHUNKS_PER_ROW 8
#define P1_THREADS 256
#define F4T      16           // float4 per thread (16 x 16B = 256B)
#define CH4      (VOCAB / 4 / CHUNKS_PER_ROW)   // 4000 float4 per block
#define LOCCAP   768
#define P2_THREADS 512
#define BITWORDS (VOCAB / 32) // 4000 words = 16000 B

typedef unsigned long long ull;

// Monotonic float->uint key: descending float order == descending unsigned order.
__device__ __forceinline__ unsigned fkey_of(float f) {
  unsigned u = __float_as_uint(f);
  return (u & 0x80000000u) ? ~u : (u | 0x80000000u);
}
__device__ __forceinline__ float f_of_key(unsigned k) {
  unsigned u = (k & 0x80000000u) ? (k & 0x7FFFFFFFu) : ~k;
  return __uint_as_float(u);
}

// ---------------- Phase 1: PURE-READ scan. d_out zeroing is done by
// hipMemsetAsync (fill kernel measured at 6.4 TB/s). The max-reduce over all
// 16 float4 forces the compiler to keep every load live -> 16 outstanding
// loads per thread (the R3 version collapsed to VGPR=24 / ~1 outstanding).
__global__ __launch_bounds__(P1_THREADS) void phase1_kernel(
    const float* __restrict__ logits,
    int* __restrict__ cnt_g, ull* __restrict__ cand)
{
  __shared__ ull cand_loc[LOCCAP];
  __shared__ int s_n, s_base;
  if (threadIdx.x == 0) s_n = 0;
  __syncthreads();

  const int blk = blockIdx.x;
  const int b   = blk >> 3;          // / CHUNKS_PER_ROW
  const int c   = blk & 7;
  const float4* row4 = (const float4*)(logits + (size_t)b * VOCAB) + (size_t)c * CH4;
  const int base_idx = c * CH4 * 4;
  const int t = threadIdx.x;

  // ---- batched independent loads (16 outstanding per thread) ----
  float4 vals[F4T];
  #pragma unroll
  for (int u = 0; u < F4T; ++u) {
    int i = t + u * P1_THREADS;
    vals[u] = (i < CH4) ? row4[i]
                        : make_float4(-1e30f, -1e30f, -1e30f, -1e30f);
  }
  // ---- max-reduce consumes ALL vals: forces batched issue; fast common path ----
  float mx = -1e30f;
  #pragma unroll
  for (int u = 0; u < F4T; ++u) {
    float m01 = fmaxf(vals[u].x, vals[u].y);
    float m23 = fmaxf(vals[u].z, vals[u].w);
    mx = fmaxf(mx, fmaxf(m01, m23));
  }
  // ---- rare path: detailed scan + LDS append ----
  if (mx > T_RAW) {
    #pragma unroll
    for (int u = 0; u < F4T; ++u) {
      int i = t + u * P1_THREADS;
      float vv[4] = {vals[u].x, vals[u].y, vals[u].z, vals[u].w};
      #pragma unroll
      for (int l = 0; l < 4; ++l) {
        if (vv[l] > T_RAW) {
          int p = atomicAdd(&s_n, 1);
          if (p < LOCCAP)
            cand_loc[p] = ((ull)fkey_of(vv[l]) << 32) |
                          (unsigned)(~(unsigned)(base_idx + i * 4 + l));
        }
      }
    }
  }
  __syncthreads();

  // ---- flush to per-row global list (one global atomic per block) ----
  int n = s_n;
  bool overflow = (n > LOCCAP);
  if (overflow) n = LOCCAP;
  if (threadIdx.x == 0)
    s_base = atomicAdd(&cnt_g[b], n + (overflow ? (1 << 20) : 0));
  __syncthreads();
  const int base = s_base;
  for (int i = threadIdx.x; i < n; i += P1_THREADS) {
    int p = base + i;
    if (p < CAP) cand[(size_t)b * CAP + p] = cand_loc[i];
  }
}

// ---------------- Phase 2: per-row penalty + sort + topk/topp + scatter ----------------
__global__ __launch_bounds__(P2_THREADS) void phase2_kernel(
    const float* __restrict__ logits, const int* __restrict__ prev,
    float* __restrict__ out, const int* __restrict__ cnt_g,
    const ull* __restrict__ cand)
{
  __shared__ unsigned bitmask[BITWORDS];          // 16000 B
  __shared__ ull keys[CAP];                       // 16384 B
  __shared__ float evals[CAP];                    //  8192 B
  __shared__ int s_cnt, s_m, s_j;
  __shared__ float s_Z2;

  const int b = blockIdx.x, tid = threadIdx.x;

  // seen-token bitmask
  for (int i = tid; i < BITWORDS; i += P2_THREADS) bitmask[i] = 0u;
  __syncthreads();
  for (int i = tid; i < HIST; i += P2_THREADS) {
    int t = prev[b * HIST + i];
    atomicOr(&bitmask[t >> 5], 1u << (t & 31));
  }
  __syncthreads();

  const int cnt_raw = cnt_g[b];   // block-uniform
  if (cnt_raw >= MINCNT && cnt_raw <= CAP) {
    // fast path: penalize + temperature on collected candidates only
    for (int i = tid; i < cnt_raw; i += P2_THREADS) {
      ull key = cand[(size_t)b * CAP + i];
      unsigned iv = (unsigned)(key & 0xFFFFFFFFull);
      int idx = (int)(~iv);
      float v = f_of_key((unsigned)(key >> 32));
      float y = v;
      if ((bitmask[idx >> 5] >> (idx & 31)) & 1u)
        y = (v < 0.0f) ? v * 1.2f : v / 1.2f;
      float x = y / 0.6f;
      keys[i] = ((ull)fkey_of(x) << 32) | iv;
    }
    if (tid == 0) s_cnt = cnt_raw;
    __syncthreads();
  } else {
    // robust fallback: rescan row with bisection on post-penalty threshold
    const float* row = logits + (size_t)b * VOCAB;
    float T = 3.0f, Tlo = 0.f, Thi = 0.f;
    bool hasLo = false, hasHi = false;
    int c2 = 0;
    for (int attempt = 0; attempt < 40; ++attempt) {
      __syncthreads();
      if (tid == 0) s_cnt = 0;
      __syncthreads();
      for (int i = tid; i < VOCAB; i += P2_THREADS) {
        float v = row[i];
        float y = v;
        if ((bitmask[i >> 5] >> (i & 31)) & 1u)
          y = (v < 0.0f) ? v * 1.2f : v / 1.2f;
        if (y > T) {
          int pos = atomicAdd(&s_cnt, 1);
          if (pos < CAP) {
            float x = y / 0.6f;
            keys[pos] = ((ull)fkey_of(x) << 32) | (unsigned)(~(unsigned)i);
          }
        }
      }
      __syncthreads();
      c2 = s_cnt;
      if (c2 >= TOPK && c2 <= CAP) break;
      if (c2 < TOPK) { Thi = T; hasHi = true; T = hasLo ? 0.5f * (T + Tlo) : T - 1.0f; }
      else           { Tlo = T; hasLo = true; T = hasHi ? 0.5f * (T + Thi) : T + 1.0f; }
    }
    __syncthreads();
    if (tid == 0 && s_cnt > CAP) s_cnt = CAP;
    __syncthreads();
  }
  const int m_cnt = s_cnt;

  // bitonic sort descending, padded to pow2
  int n = 64;
  while (n < m_cnt) n <<= 1;
  for (int i = m_cnt + tid; i < n; i += P2_THREADS) keys[i] = 0ull;
  __syncthreads();
  for (int k = 2; k <= n; k <<= 1) {
    for (int j = k >> 1; j > 0; j >>= 1) {
      for (int i = tid; i < n; i += P2_THREADS) {
        int l = i ^ j;
        if (l > i) {
          ull a = keys[i], cc = keys[l];
          bool up = (i & k) == 0;
          if (up ? (a < cc) : (a > cc)) { keys[i] = cc; keys[l] = a; }
        }
      }
      __syncthreads();
    }
  }

  // top-k boundary (keep ties at kth)
  if (tid == 0) {
    int kk = (m_cnt < TOPK) ? m_cnt : TOPK;
    unsigned kth = (unsigned)(keys[kk - 1] >> 32);
    int m = kk;
    while (m < m_cnt && (unsigned)(keys[m] >> 32) == kth) m++;
    s_m = m;
  }
  __syncthreads();
  const int m = s_m;
  const float maxx = f_of_key((unsigned)(keys[0] >> 32));
  for (int i = tid; i < m; i += P2_THREADS)
    evals[i] = expf(f_of_key((unsigned)(keys[i] >> 32)) - maxx);
  __syncthreads();

  // nucleus cutoff: keep token i iff i==0 or cumsum(p[0..i-1]) <= 0.9
  if (tid == 0) {
    float Z = 0.f;
    for (int i = 0; i < m; ++i) Z += evals[i];
    float cum = 0.f;
    int j = 0;
    for (int i = 0; i < m; ++i) {
      if (i > 0 && cum > 0.9f) break;
      cum += evals[i] / Z;
      j = i + 1;
    }
    float Z2 = 0.f;
    for (int i = 0; i < j; ++i) Z2 += evals[i];
    s_j = j; s_Z2 = Z2;
  }
  __syncthreads();

  // scatter final probs (row zeroed by the hipMemsetAsync fill)
  for (int i = tid; i < s_j; i += P2_THREADS) {
    int idx = (int)(~(unsigned)(keys[i] & 0xFFFFFFFFull));
    out[(size_t)b * VOCAB + idx] = evals[i] / s_Z2;
  }
}

// ---------------- Legacy single-kernel path (ws_size fallback) ----------------
__global__ __launch_bounds__(1024) void sample_head_kernel(
    const float* __restrict__ logits, const int* __restrict__ prev,
    float* __restrict__ out)
{
  __shared__ unsigned bitmask[BITWORDS];
  __shared__ ull keys[CAP];
  __shared__ float evals[CAP];
  __shared__ int s_count;
  __shared__ int s_m, s_j;
  __shared__ float s_maxx, s_Z2;

  const int b   = blockIdx.x;
  const int tid = threadIdx.x;
  const float* row  = logits + (size_t)b * VOCAB;
  float*       orow = out    + (size_t)b * VOCAB;

  for (int i = tid; i < BITWORDS; i += 1024) bitmask[i] = 0u;
  __syncthreads();
  for (int i = tid; i < HIST; i += 1024) {
    int t = prev[b * HIST + i];
    atomicOr(&bitmask[t >> 5], 1u << (t & 31));
  }
  __syncthreads();

  float T = 3.0f;
  float Tlo = 0.f, Thi = 0.f;
  bool hasLo = false, hasHi = false;
  int cnt = 0;

  const float4* row4  = (const float4*)row;
  float4*       orow4 = (float4*)orow;
  const int N4 = VOCAB / 4;

  for (int attempt = 0; attempt < 40; ++attempt) {
    __syncthreads();
    if (tid == 0) s_count = 0;
    __syncthreads();
    for (int i = tid; i < N4; i += 1024) {
      float4 v4 = row4[i];
      if (attempt == 0) orow4[i] = make_float4(0.f, 0.f, 0.f, 0.f);
      int v0 = i * 4;
      unsigned w  = bitmask[v0 >> 5];
      unsigned sh = v0 & 31;
      float vv[4] = {v4.x, v4.y, v4.z, v4.w};
      #pragma unroll
      for (int l = 0; l < 4; ++l) {
        float v = vv[l];
        float y = v;
        if ((w >> (sh + l)) & 1u)
          y = (v < 0.0f) ? v * 1.2f : v / 1.2f;
        if (y > T) {
          float x = y / 0.6f;
          int pos = atomicAdd(&s_count, 1);
          if (pos < CAP) {
            keys[pos] = ((ull)fkey_of(x) << 32) | (unsigned)(~(unsigned)(v0 + l));
          }
        }
      }
    }
    __syncthreads();
    cnt = s_count;
    if (cnt >= TOPK && cnt <= CAP) break;
    if (cnt < TOPK) { Thi = T; hasHi = true; T = hasLo ? 0.5f * (T + Tlo) : T - 1.0f; }
    else            { Tlo = T; hasLo = true; T = hasHi ? 0.5f * (T + Thi) : T + 1.0f; }
  }
  if (cnt > CAP) cnt = CAP;

  int n = 64;
  while (n < cnt) n <<= 1;
  for (int i = cnt + tid; i < n; i += 1024) keys[i] = 0ull;
  __syncthreads();
  for (int k = 2; k <= n; k <<= 1) {
    for (int j = k >> 1; j > 0; j >>= 1) {
      for (int i = tid; i < n; i += 1024) {
        int l = i ^ j;
        if (l > i) {
          ull a = keys[i], c = keys[l];
          bool up = (i & k) == 0;
          if (up ? (a < c) : (a > c)) { keys[i] = c; keys[l] = a; }
        }
      }
      __syncthreads();
    }
  }

  if (tid == 0) {
    int kk = (cnt < TOPK) ? cnt : TOPK;
    unsigned kth = (unsigned)(keys[kk - 1] >> 32);
    int m = kk;
    while (m < cnt && (unsigned)(keys[m] >> 32) == kth) m++;
    s_m = m;
    s_maxx = f_of_key((unsigned)(keys[0] >> 32));
  }
  __syncthreads();
  int m = s_m;
  float maxx = s_maxx;
  for (int i = tid; i < m; i += 1024)
    evals[i] = expf(f_of_key((unsigned)(keys[i] >> 32)) - maxx);
  __syncthreads();

  if (tid == 0) {
    float Z = 0.f;
    for (int i = 0; i < m; ++i) Z += evals[i];
    float cum = 0.f;
    int j = 0;
    for (int i = 0; i < m; ++i) {
      if (i > 0 && cum > 0.9f) break;
      cum += evals[i] / Z;
      j = i + 1;
    }
    float Z2 = 0.f;
    for (int i = 0; i < j; ++i) Z2 += evals[i];
    s_j = j; s_Z2 = Z2;
  }
  __syncthreads();

  int j = s_j;
  float Z2 = s_Z2;
  for (int i = tid; i < j; i += 1024) {
    int idx = (int)(~(unsigned)(keys[i] & 0xFFFFFFFFull));
    orow[idx] = evals[i] / Z2;
  }
}

extern "C" void kernel_launch(void* const* d_in, const int* in_sizes, int n_in,
                              void* d_out, int out_size, void* d_ws, size_t ws_size,
                              hipStream_t stream) {
  const float* logits = (const float*)d_in[0];
  const int*   prev   = (const int*)d_in[1];
  float*       out    = (float*)d_out;

  const size_t need = 1024 + (size_t)BATCH * CAP * sizeof(ull);
  if (ws_size >= need) {
    int* cnt = (int*)d_ws;
    ull* cand = (ull*)((char*)d_ws + 1024);
    // zero the candidate counters (1 KB) and the whole output (fill kernel
    // runs at ~6.4 TB/s — faster than any hand-written fused zero-store).
    hipMemsetAsync(d_ws, 0, BATCH * sizeof(int), stream);
    hipMemsetAsync(d_out, 0, (size_t)out_size * sizeof(float), stream);
    hipLaunchKernelGGL(phase1_kernel, dim3(BATCH * CHUNKS_PER_ROW), dim3(P1_THREADS),
                       0, stream, logits, cnt, cand);
    hipLaunchKernelGGL(phase2_kernel, dim3(BATCH), dim3(P2_THREADS),
                       0, stream, logits, prev, out, cnt, cand);
  } else {
    hipLaunchKernelGGL(sample_head_kernel, dim3(BATCH), dim3(1024), 0, stream,
                       logits, prev, out);
  }
}

// Round 6
// 255.765 us; speedup vs baseline: 1.4517x; 1.0212x over previous
//
#include <hip/hip_runtime.h>
#include <stdint.h>

#define BATCH    256
#define VOCAB    128000
#define HIST     200
#define TOPK     50
#define CAP      2048
#define MINCNT   250          // >=250 raw candidates => superset of post-penalty top-k
#define T_RAW    2.6f         // expected count(v>2.6) ~ 596 per row for N(0,1)
#define CHUNKS_PER_ROW 8
#define NCHUNK   (BATCH * CHUNKS_PER_ROW)       // 2048 chunk slots
#define CNT_BYTES 16384       // cnt8 region: 2048*4 = 8192 B, padded to 16 KB (R5 bug: was 4096 -> overlap!)
#define P1_THREADS 256
#define F4T      16           // 15 unguarded + 1 guarded (4000 = 15*256 + 160)
#define CH4      (VOCAB / 4 / CHUNKS_PER_ROW)   // 4000 float4 per block
#define SEGCAP   256          // per-chunk candidate segment (exp ~75, 256 is >17 sigma)
#define LOCCAP   512
#define P2_THREADS 1024
#define BITWORDS (VOCAB / 32) // 4000 words = 16000 B

typedef unsigned long long ull;

// Monotonic float->uint key: descending float order == descending unsigned order.
__device__ __forceinline__ unsigned fkey_of(float f) {
  unsigned u = __float_as_uint(f);
  return (u & 0x80000000u) ? ~u : (u | 0x80000000u);
}
__device__ __forceinline__ float f_of_key(unsigned k) {
  unsigned u = (k & 0x80000000u) ? (k & 0x7FFFFFFFu) : ~k;
  return __uint_as_float(u);
}

// ---------------- Phase 1: pure-read scan. No global atomics, no pre-zeroed
// state: each (row,chunk) block owns slot cnt8[b*8+c] and candidate segment
// cand[(b*8+c)*SEGCAP ...], both written unconditionally.
__global__ __launch_bounds__(P1_THREADS) void phase1_kernel(
    const float* __restrict__ logits,
    int* __restrict__ cnt8, ull* __restrict__ cand)
{
  __shared__ ull cand_loc[LOCCAP];
  __shared__ int s_n;
  if (threadIdx.x == 0) s_n = 0;
  __syncthreads();

  const int blk = blockIdx.x;
  const int b   = blk >> 3;          // / CHUNKS_PER_ROW
  const int c   = blk & 7;
  const float4* row4 = (const float4*)(logits + (size_t)b * VOCAB) + (size_t)c * CH4;
  const int base_idx = c * CH4 * 4;
  const int t = threadIdx.x;

  // ---- batched loads: 15 unconditional + 1 guarded ----
  float4 vals[F4T];
  #pragma unroll
  for (int u = 0; u < F4T - 1; ++u)
    vals[u] = row4[t + u * P1_THREADS];
  {
    int i = t + (F4T - 1) * P1_THREADS;
    vals[F4T - 1] = (i < CH4) ? row4[i]
                              : make_float4(-1e30f, -1e30f, -1e30f, -1e30f);
  }
  // ---- max-reduce consumes ALL vals (keeps loads batched); fast common path ----
  float mx = -1e30f;
  #pragma unroll
  for (int u = 0; u < F4T; ++u) {
    float m01 = fmaxf(vals[u].x, vals[u].y);
    float m23 = fmaxf(vals[u].z, vals[u].w);
    mx = fmaxf(mx, fmaxf(m01, m23));
  }
  // ---- rare path: detailed scan + LDS append ----
  if (mx > T_RAW) {
    #pragma unroll
    for (int u = 0; u < F4T; ++u) {
      int i = t + u * P1_THREADS;
      float vv[4] = {vals[u].x, vals[u].y, vals[u].z, vals[u].w};
      #pragma unroll
      for (int l = 0; l < 4; ++l) {
        if (vv[l] > T_RAW && i < CH4) {
          int p = atomicAdd(&s_n, 1);
          if (p < LOCCAP)
            cand_loc[p] = ((ull)fkey_of(vv[l]) << 32) |
                          (unsigned)(~(unsigned)(base_idx + i * 4 + l));
        }
      }
    }
  }
  __syncthreads();

  // ---- unconditional per-chunk flush: raw count + up to SEGCAP candidates ----
  const int n = s_n;
  if (t == 0) cnt8[blk] = n;          // n > SEGCAP signals phase2 fallback
  const int nf = (n < SEGCAP) ? n : SEGCAP;
  for (int i = t; i < nf; i += P1_THREADS)
    cand[(size_t)blk * SEGCAP + i] = cand_loc[i];
}

// ---------------- Phase 2: per-row penalty + sort + topk/topp + scatter ----------------
__global__ __launch_bounds__(P2_THREADS) void phase2_kernel(
    const float* __restrict__ logits, const int* __restrict__ prev,
    float* __restrict__ out, const int* __restrict__ cnt8,
    const ull* __restrict__ cand)
{
  __shared__ unsigned bitmask[BITWORDS];          // 16000 B
  __shared__ ull keys[CAP];                       // 16384 B
  __shared__ float evals[CAP];                    //  8192 B
  __shared__ int s_cnt, s_m, s_j;
  __shared__ float s_Z2;

  const int b = blockIdx.x, tid = threadIdx.x;

  // seen-token bitmask
  for (int i = tid; i < BITWORDS; i += P2_THREADS) bitmask[i] = 0u;
  __syncthreads();
  for (int i = tid; i < HIST; i += P2_THREADS) {
    int t = prev[b * HIST + i];
    atomicOr(&bitmask[t >> 5], 1u << (t & 31));
  }
  __syncthreads();

  // per-chunk counts -> prefix offsets (redundant in every thread; 8 cached loads)
  int n_c[CHUNKS_PER_ROW], off_c[CHUNKS_PER_ROW];
  int total = 0;
  bool ok = true;
  #pragma unroll
  for (int c = 0; c < CHUNKS_PER_ROW; ++c) {
    int n = cnt8[b * CHUNKS_PER_ROW + c];
    n_c[c] = n; off_c[c] = total; total += n;
    if ((unsigned)n > (unsigned)SEGCAP) ok = false;  // unsigned: catches negatives too
  }
  if (total < MINCNT || total > CAP) ok = false;

  if (ok) {
    // fast path: gather 8 segments, apply penalty + temperature
    #pragma unroll
    for (int c = 0; c < CHUNKS_PER_ROW; ++c) {
      const ull* seg = cand + (size_t)(b * CHUNKS_PER_ROW + c) * SEGCAP;
      for (int i = tid; i < n_c[c]; i += P2_THREADS) {
        ull key = seg[i];
        unsigned iv = (unsigned)(key & 0xFFFFFFFFull);
        int idx = (int)(~iv);
        float v = f_of_key((unsigned)(key >> 32));
        float y = v;
        if ((bitmask[idx >> 5] >> (idx & 31)) & 1u)
          y = (v < 0.0f) ? v * 1.2f : v / 1.2f;
        float x = y / 0.6f;
        keys[off_c[c] + i] = ((ull)fkey_of(x) << 32) | iv;
      }
    }
    if (tid == 0) s_cnt = total;
    __syncthreads();
  } else {
    // robust fallback: rescan row with bisection on post-penalty threshold
    const float* row = logits + (size_t)b * VOCAB;
    float T = 3.0f, Tlo = 0.f, Thi = 0.f;
    bool hasLo = false, hasHi = false;
    int c2 = 0;
    for (int attempt = 0; attempt < 40; ++attempt) {
      __syncthreads();
      if (tid == 0) s_cnt = 0;
      __syncthreads();
      for (int i = tid; i < VOCAB; i += P2_THREADS) {
        float v = row[i];
        float y = v;
        if ((bitmask[i >> 5] >> (i & 31)) & 1u)
          y = (v < 0.0f) ? v * 1.2f : v / 1.2f;
        if (y > T) {
          int pos = atomicAdd(&s_cnt, 1);
          if (pos < CAP) {
            float x = y / 0.6f;
            keys[pos] = ((ull)fkey_of(x) << 32) | (unsigned)(~(unsigned)i);
          }
        }
      }
      __syncthreads();
      c2 = s_cnt;
      if (c2 >= TOPK && c2 <= CAP) break;
      if (c2 < TOPK) { Thi = T; hasHi = true; T = hasLo ? 0.5f * (T + Tlo) : T - 1.0f; }
      else           { Tlo = T; hasLo = true; T = hasHi ? 0.5f * (T + Thi) : T + 1.0f; }
    }
    __syncthreads();
    if (tid == 0 && s_cnt > CAP) s_cnt = CAP;
    __syncthreads();
  }
  const int m_cnt = s_cnt;

  // bitonic sort descending, padded to pow2
  int n = 64;
  while (n < m_cnt) n <<= 1;
  for (int i = m_cnt + tid; i < n; i += P2_THREADS) keys[i] = 0ull;
  __syncthreads();
  for (int k = 2; k <= n; k <<= 1) {
    for (int j = k >> 1; j > 0; j >>= 1) {
      for (int i = tid; i < n; i += P2_THREADS) {
        int l = i ^ j;
        if (l > i) {
          ull a = keys[i], cc = keys[l];
          bool up = (i & k) == 0;
          if (up ? (a < cc) : (a > cc)) { keys[i] = cc; keys[l] = a; }
        }
      }
      __syncthreads();
    }
  }

  // top-k boundary (keep ties at kth)
  if (tid == 0) {
    int kk = (m_cnt < TOPK) ? m_cnt : TOPK;
    unsigned kth = (unsigned)(keys[kk - 1] >> 32);
    int m = kk;
    while (m < m_cnt && (unsigned)(keys[m] >> 32) == kth) m++;
    s_m = m;
  }
  __syncthreads();
  const int m = s_m;
  const float maxx = f_of_key((unsigned)(keys[0] >> 32));
  for (int i = tid; i < m; i += P2_THREADS)
    evals[i] = expf(f_of_key((unsigned)(keys[i] >> 32)) - maxx);
  __syncthreads();

  // nucleus cutoff: keep token i iff i==0 or cumsum(p[0..i-1]) <= 0.9
  if (tid == 0) {
    float Z = 0.f;
    for (int i = 0; i < m; ++i) Z += evals[i];
    float cum = 0.f;
    int j = 0;
    for (int i = 0; i < m; ++i) {
      if (i > 0 && cum > 0.9f) break;
      cum += evals[i] / Z;
      j = i + 1;
    }
    float Z2 = 0.f;
    for (int i = 0; i < j; ++i) Z2 += evals[i];
    s_j = j; s_Z2 = Z2;
  }
  __syncthreads();

  // scatter final probs (row zeroed by the hipMemsetAsync fill)
  for (int i = tid; i < s_j; i += P2_THREADS) {
    int idx = (int)(~(unsigned)(keys[i] & 0xFFFFFFFFull));
    out[(size_t)b * VOCAB + idx] = evals[i] / s_Z2;
  }
}

// ---------------- Legacy single-kernel path (ws_size fallback) ----------------
__global__ __launch_bounds__(1024) void sample_head_kernel(
    const float* __restrict__ logits, const int* __restrict__ prev,
    float* __restrict__ out)
{
  __shared__ unsigned bitmask[BITWORDS];
  __shared__ ull keys[CAP];
  __shared__ float evals[CAP];
  __shared__ int s_count;
  __shared__ int s_m, s_j;
  __shared__ float s_maxx, s_Z2;

  const int b   = blockIdx.x;
  const int tid = threadIdx.x;
  const float* row  = logits + (size_t)b * VOCAB;
  float*       orow = out    + (size_t)b * VOCAB;

  for (int i = tid; i < BITWORDS; i += 1024) bitmask[i] = 0u;
  __syncthreads();
  for (int i = tid; i < HIST; i += 1024) {
    int t = prev[b * HIST + i];
    atomicOr(&bitmask[t >> 5], 1u << (t & 31));
  }
  __syncthreads();

  float T = 3.0f;
  float Tlo = 0.f, Thi = 0.f;
  bool hasLo = false, hasHi = false;
  int cnt = 0;

  const float4* row4  = (const float4*)row;
  float4*       orow4 = (float4*)orow;
  const int N4 = VOCAB / 4;

  for (int attempt = 0; attempt < 40; ++attempt) {
    __syncthreads();
    if (tid == 0) s_count = 0;
    __syncthreads();
    for (int i = tid; i < N4; i += 1024) {
      float4 v4 = row4[i];
      if (attempt == 0) orow4[i] = make_float4(0.f, 0.f, 0.f, 0.f);
      int v0 = i * 4;
      unsigned w  = bitmask[v0 >> 5];
      unsigned sh = v0 & 31;
      float vv[4] = {v4.x, v4.y, v4.z, v4.w};
      #pragma unroll
      for (int l = 0; l < 4; ++l) {
        float v = vv[l];
        float y = v;
        if ((w >> (sh + l)) & 1u)
          y = (v < 0.0f) ? v * 1.2f : v / 1.2f;
        if (y > T) {
          float x = y / 0.6f;
          int pos = atomicAdd(&s_count, 1);
          if (pos < CAP) {
            keys[pos] = ((ull)fkey_of(x) << 32) | (unsigned)(~(unsigned)(v0 + l));
          }
        }
      }
    }
    __syncthreads();
    cnt = s_count;
    if (cnt >= TOPK && cnt <= CAP) break;
    if (cnt < TOPK) { Thi = T; hasHi = true; T = hasLo ? 0.5f * (T + Tlo) : T - 1.0f; }
    else            { Tlo = T; hasLo = true; T = hasHi ? 0.5f * (T + Thi) : T + 1.0f; }
  }
  if (cnt > CAP) cnt = CAP;

  int n = 64;
  while (n < cnt) n <<= 1;
  for (int i = cnt + tid; i < n; i += 1024) keys[i] = 0ull;
  __syncthreads();
  for (int k = 2; k <= n; k <<= 1) {
    for (int j = k >> 1; j > 0; j >>= 1) {
      for (int i = tid; i < n; i += 1024) {
        int l = i ^ j;
        if (l > i) {
          ull a = keys[i], c = keys[l];
          bool up = (i & k) == 0;
          if (up ? (a < c) : (a > c)) { keys[i] = c; keys[l] = a; }
        }
      }
      __syncthreads();
    }
  }

  if (tid == 0) {
    int kk = (cnt < TOPK) ? cnt : TOPK;
    unsigned kth = (unsigned)(keys[kk - 1] >> 32);
    int m = kk;
    while (m < cnt && (unsigned)(keys[m] >> 32) == kth) m++;
    s_m = m;
    s_maxx = f_of_key((unsigned)(keys[0] >> 32));
  }
  __syncthreads();
  int m = s_m;
  float maxx = s_maxx;
  for (int i = tid; i < m; i += 1024)
    evals[i] = expf(f_of_key((unsigned)(keys[i] >> 32)) - maxx);
  __syncthreads();

  if (tid == 0) {
    float Z = 0.f;
    for (int i = 0; i < m; ++i) Z += evals[i];
    float cum = 0.f;
    int j = 0;
    for (int i = 0; i < m; ++i) {
      if (i > 0 && cum > 0.9f) break;
      cum += evals[i] / Z;
      j = i + 1;
    }
    float Z2 = 0.f;
    for (int i = 0; i < j; ++i) Z2 += evals[i];
    s_j = j; s_Z2 = Z2;
  }
  __syncthreads();

  int j = s_j;
  float Z2 = s_Z2;
  for (int i = tid; i < j; i += 1024) {
    int idx = (int)(~(unsigned)(keys[i] & 0xFFFFFFFFull));
    orow[idx] = evals[i] / Z2;
  }
}

extern "C" void kernel_launch(void* const* d_in, const int* in_sizes, int n_in,
                              void* d_out, int out_size, void* d_ws, size_t ws_size,
                              hipStream_t stream) {
  const float* logits = (const float*)d_in[0];
  const int*   prev   = (const int*)d_in[1];
  float*       out    = (float*)d_out;

  const size_t need = CNT_BYTES + (size_t)NCHUNK * SEGCAP * sizeof(ull);
  if (ws_size >= need) {
    int* cnt8 = (int*)d_ws;                          // NCHUNK ints (8192 B), written unconditionally
    ull* cand = (ull*)((char*)d_ws + CNT_BYTES);     // starts AFTER cnt8 (R5 bug: started at 4096)
    // zero the whole output (fill kernel runs at ~6.6 TB/s; faster than any
    // hand-written fused zero-store). No other pre-zeroing needed.
    hipMemsetAsync(d_out, 0, (size_t)out_size * sizeof(float), stream);
    hipLaunchKernelGGL(phase1_kernel, dim3(NCHUNK), dim3(P1_THREADS),
                       0, stream, logits, cnt8, cand);
    hipLaunchKernelGGL(phase2_kernel, dim3(BATCH), dim3(P2_THREADS),
                       0, stream, logits, prev, out, cnt8, cand);
  } else {
    hipLaunchKernelGGL(sample_head_kernel, dim3(BATCH), dim3(1024), 0, stream,
                       logits, prev, out);
  }
}